// Round 4
// baseline (1368.441 us; speedup 1.0000x reference)
//
#include <hip/hip_runtime.h>
#include <stdint.h>

#define DTv 0.2f

typedef __attribute__((ext_vector_type(8))) short short8;
typedef __attribute__((ext_vector_type(4))) float f32x4;

// ---------------- threefry2x32, bit-exact to JAX (partitionable) ----------------
__device__ __forceinline__ uint32_t rotl32(uint32_t v, uint32_t r){ return (v<<r)|(v>>(32u-r)); }

__device__ __forceinline__ void tf2x32(uint32_t k0, uint32_t k1, uint32_t& x0, uint32_t& x1){
  const uint32_t k2 = k0 ^ k1 ^ 0x1BD11BDAu;
  x0 += k0; x1 += k1;
#define RND(r) { x0 += x1; x1 = rotl32(x1,(r)); x1 ^= x0; }
  RND(13u) RND(15u) RND(26u) RND(6u)
  x0 += k1; x1 += k2 + 1u;
  RND(17u) RND(29u) RND(16u) RND(24u)
  x0 += k2; x1 += k0 + 2u;
  RND(13u) RND(15u) RND(26u) RND(6u)
  x0 += k0; x1 += k1 + 3u;
  RND(17u) RND(29u) RND(16u) RND(24u)
  x0 += k1; x1 += k2 + 4u;
  RND(13u) RND(15u) RND(26u) RND(6u)
  x0 += k2; x1 += k0 + 5u;
#undef RND
}

__device__ __forceinline__ float u01(uint32_t bits){
  return __uint_as_float((bits >> 9) | 0x3f800000u) - 1.0f;
}

__device__ inline void step_keys(int t, uint32_t* K){
  uint32_t c0 = 0u, c1 = (uint32_t)t;
  tf2x32(0u, 42u, c0, c1);
#pragma unroll
  for (int i = 0; i < 3; ++i){
    uint32_t a = 0u, b = (uint32_t)i;
    tf2x32(c0, c1, a, b);
    K[2*i] = a; K[2*i+1] = b;
  }
}

// ---------------- bf16 helpers (RNE) ----------------
__device__ __forceinline__ ushort f2bf(float f){
  uint32_t u = __float_as_uint(f);
  u += 0x7fffu + ((u >> 16) & 1u);
  return (ushort)(u >> 16);
}
__device__ __forceinline__ float bf2f(ushort h){ return __uint_as_float(((uint32_t)h) << 16); }

// ---------------- spike generation for t=0 ----------------
__global__ __launch_bounds__(256) void spike_kernel(
    const float* __restrict__ s0, const float* __restrict__ s1, const float* __restrict__ s2,
    float* __restrict__ sp0, float* __restrict__ sp1, ushort* __restrict__ sp2b, int t)
{
  __shared__ uint32_t K[6];
  if (threadIdx.x == 0) step_keys(t, K);
  __syncthreads();
  const int g = blockIdx.x * 256 + threadIdx.x;
  const int E0 = 2560, E1 = E0 + 262144;
  if (g < E0){
    uint32_t x0 = 0u, x1 = (uint32_t)g;
    tf2x32(K[0], K[1], x0, x1);
    const float r = fminf(fmaxf(s0[g], 0.f), 1.f);
    sp0[g] = (u01(x0 ^ x1) < r) ? 1.0f : 0.0f;
  } else if (g < E1){
    const int n = g - E0;
    uint32_t x0 = 0u, x1 = (uint32_t)n;
    tf2x32(K[2], K[3], x0, x1);
    const float r = fminf(fmaxf(s1[n], 0.f), 1.f);
    sp1[n] = (u01(x0 ^ x1) < r) ? 1.0f : 0.0f;
  } else {
    const int n = g - E1;
    uint32_t x0 = 0u, x1 = (uint32_t)n;
    tf2x32(K[4], K[5], x0, x1);
    const float r = fminf(fmaxf(s2[n], 0.f), 1.f);
    sp2b[n] = (u01(x0 ^ x1) < r) ? (ushort)0x3F80u : (ushort)0u;
  }
}

// ---------------- init / final ----------------
__global__ __launch_bounds__(256) void init_kernel(
    const float* __restrict__ s0i, const float* __restrict__ s1i, const float* __restrict__ s2i,
    const float* __restrict__ data,
    float* __restrict__ b0s, float* __restrict__ b1s, float* __restrict__ b2s,
    ushort* __restrict__ ah, ushort* __restrict__ al,
    float* __restrict__ out_data)
{
  const int i = blockIdx.x*256 + threadIdx.x;
  if (i < 2560)   b0s[i] = s0i[i];
  if (i < 262144){
    b1s[i] = s1i[i]; b2s[i] = s2i[i];
    const float v = fminf(fmaxf(s1i[i], 0.f), 1.f);   // rho(s1)
    const ushort h = f2bf(v);
    ah[i] = h; al[i] = f2bf(v - bf2f(h));
  }
  if (i < 200704) out_data[i] = data[i];
}

__global__ __launch_bounds__(256) void final_kernel(
    const float* __restrict__ b0s, const float* __restrict__ b1s, const float* __restrict__ b2s,
    float* __restrict__ out)
{
  const int i = blockIdx.x*256 + threadIdx.x;
  if (i < 2560)   out[i] = b0s[i];
  if (i < 262144){ out[2560+i] = b1s[i]; out[264704+i] = b2s[i]; }
}

// ---------------- weight split: W -> (Wh, Wl) bf16, elementwise ----------------
// NOTE: W3 == W2^T by construction, so B-transposed(GEMM1) = W2 flat, B-transposed(GEMM2) = W3 flat.
__global__ __launch_bounds__(256) void wsplit_kernel(
    const float* __restrict__ W2, const float* __restrict__ W3,
    ushort* __restrict__ W2h, ushort* __restrict__ W2l,
    ushort* __restrict__ W3h, ushort* __restrict__ W3l)
{
  int idx = (blockIdx.x*256 + threadIdx.x) << 2;
  const float* W; ushort *H, *L;
  if (idx < 1048576){ W = W2; H = W2h; L = W2l; }
  else { idx -= 1048576; W = W3; H = W3h; L = W3l; }
  const float4 v = *(const float4*)&W[idx];
  const float* vp = (const float*)&v;
  ushort4 h, l;
  ushort* hp = (ushort*)&h; ushort* lp = (ushort*)&l;
#pragma unroll
  for (int j=0;j<4;j++){
    hp[j] = f2bf(vp[j]);
    lp[j] = f2bf(vp[j] - bf2f(hp[j]));
  }
  *(ushort4*)&H[idx] = h;
  *(ushort4*)&L[idx] = l;
}

// ---------------- D2 partials: data @ W4^T, split-K 7x112 ----------------
__global__ __launch_bounds__(256) void d2p_kernel(
    const float* __restrict__ data, const float* __restrict__ W4, float* __restrict__ Pd2)
{
  __shared__ float As[16][64];
  __shared__ float Bs[16][64];
  const int tb = blockIdx.x / 7;
  const int ch = blockIdx.x % 7;
  const int kb = ch * 112;
  const int R0 = (tb >> 4) << 6;
  const int C0 = (tb & 15) << 6;
  const int tid = threadIdx.x;
  const int ty = tid >> 4, tx = tid & 15;
  const int mA = tid >> 2, kqA = (tid & 3) << 2;
  float acc[4][4] = {{0.f}};
  for (int kk = 0; kk < 112; kk += 16){
    const float4 a = *(const float4*)&data[(R0+mA)*784 + kb + kk + kqA];
    As[kqA+0][mA]=a.x; As[kqA+1][mA]=a.y; As[kqA+2][mA]=a.z; As[kqA+3][mA]=a.w;
    const float4 b = *(const float4*)&W4[(C0+mA)*784 + kb + kk + kqA];
    Bs[kqA+0][mA]=b.x; Bs[kqA+1][mA]=b.y; Bs[kqA+2][mA]=b.z; Bs[kqA+3][mA]=b.w;
    __syncthreads();
#pragma unroll
    for (int k=0;k<16;k++){
      const float4 av = *(const float4*)&As[k][ty<<2];
      const float4 bv = *(const float4*)&Bs[k][tx<<2];
      acc[0][0]=fmaf(av.x,bv.x,acc[0][0]); acc[0][1]=fmaf(av.x,bv.y,acc[0][1]);
      acc[0][2]=fmaf(av.x,bv.z,acc[0][2]); acc[0][3]=fmaf(av.x,bv.w,acc[0][3]);
      acc[1][0]=fmaf(av.y,bv.x,acc[1][0]); acc[1][1]=fmaf(av.y,bv.y,acc[1][1]);
      acc[1][2]=fmaf(av.y,bv.z,acc[1][2]); acc[1][3]=fmaf(av.y,bv.w,acc[1][3]);
      acc[2][0]=fmaf(av.z,bv.x,acc[2][0]); acc[2][1]=fmaf(av.z,bv.y,acc[2][1]);
      acc[2][2]=fmaf(av.z,bv.z,acc[2][2]); acc[2][3]=fmaf(av.z,bv.w,acc[2][3]);
      acc[3][0]=fmaf(av.w,bv.x,acc[3][0]); acc[3][1]=fmaf(av.w,bv.y,acc[3][1]);
      acc[3][2]=fmaf(av.w,bv.z,acc[3][2]); acc[3][3]=fmaf(av.w,bv.w,acc[3][3]);
    }
    __syncthreads();
  }
  float* P = Pd2 + ch*262144;
#pragma unroll
  for (int i=0;i<4;i++){
    const int r = R0 + (ty<<2) + i;
    float4 o; float* op=(float*)&o;
#pragma unroll
    for (int j=0;j<4;j++) op[j] = acc[i][j];
    *(float4*)&P[r*1024 + C0 + (tx<<2)] = o;
  }
}

__global__ __launch_bounds__(256) void d2r_kernel(
    const float* __restrict__ Pd2, const float* __restrict__ b4, float* __restrict__ D2)
{
  const int e = (blockIdx.x*256 + threadIdx.x) << 2;
  float4 acc = *(const float4*)&Pd2[e];
#pragma unroll
  for (int p = 1; p < 7; ++p){
    const float4 q = *(const float4*)&Pd2[p*262144 + e];
    acc.x += q.x; acc.y += q.y; acc.z += q.z; acc.w += q.w;
  }
  const float4 bb = *(const float4*)&b4[e & 1023];
  acc.x += bb.x; acc.y += bb.y; acc.z += bb.z; acc.w += bb.w;
  *(float4*)&D2[e] = acc;
}

// ---------------- MFMA GEMM kernel ----------------
// bid < 1024: 2 GEMMs x 8 rowtiles(32) x 64 coltiles(16), XCD-grouped cols.
//   GEMM1 (g2=0): C1 = sp2 @ W3  -> A = sp2b (exact), Bt = W2 (h+l)
//   GEMM2 (g2=1): C2 = rho(s1) @ W2 -> A = ah+al,     Bt = W3 (h+l)
// 4 waves: in-block split-K (256 each), LDS reduce, wave 0 writes C.
// bid >= 1024: s0 update (16 blocks).
__global__ __launch_bounds__(256, 4) void mfma_kernel(
    const ushort* __restrict__ sp2b, const ushort* __restrict__ ah, const ushort* __restrict__ al,
    const ushort* __restrict__ W2h, const ushort* __restrict__ W2l,
    const ushort* __restrict__ W3h, const ushort* __restrict__ W3l,
    const float* __restrict__ s0o, const float* __restrict__ sp1,
    const float* __restrict__ W1, const float* __restrict__ b0,
    float* __restrict__ C1, float* __restrict__ C2, float* __restrict__ s0n)
{
  const int bid = blockIdx.x;
  const int tid = threadIdx.x;
  if (bid < 1024){
    const int xcd = bid & 7;
    const int ib  = bid >> 3;
    const int coltile = xcd*8 + (ib & 7);
    const int rowtile = (ib >> 3) & 7;
    const int g2      = (ib >> 6) & 1;
    const int lane = tid & 63;
    const int w    = tid >> 6;
    const int rb = rowtile << 5, cb = coltile << 4;
    const int lr = lane & 15, lg = lane >> 4;
    const int arow0 = (rb + lr) << 10;
    const int arow1 = arow0 + (16 << 10);
    const int bcol  = (cb + lr) << 10;
    const int k0    = (w << 8) + (lg << 3);
    f32x4 acc0 = {0.f,0.f,0.f,0.f}, acc1 = {0.f,0.f,0.f,0.f};
    if (g2 == 0){
#pragma unroll
      for (int ks = 0; ks < 8; ++ks){
        const int k = k0 + (ks << 5);
        const short8 a0 = *(const short8*)(sp2b + arow0 + k);
        const short8 a1 = *(const short8*)(sp2b + arow1 + k);
        const short8 bh = *(const short8*)((const short*)W2h + bcol + k);
        const short8 bl = *(const short8*)((const short*)W2l + bcol + k);
        acc0 = __builtin_amdgcn_mfma_f32_16x16x32_bf16(a0, bh, acc0, 0,0,0);
        acc1 = __builtin_amdgcn_mfma_f32_16x16x32_bf16(a1, bh, acc1, 0,0,0);
        acc0 = __builtin_amdgcn_mfma_f32_16x16x32_bf16(a0, bl, acc0, 0,0,0);
        acc1 = __builtin_amdgcn_mfma_f32_16x16x32_bf16(a1, bl, acc1, 0,0,0);
      }
    } else {
#pragma unroll
      for (int ks = 0; ks < 8; ++ks){
        const int k = k0 + (ks << 5);
        const short8 h0 = *(const short8*)(ah + arow0 + k);
        const short8 h1 = *(const short8*)(ah + arow1 + k);
        const short8 l0 = *(const short8*)(al + arow0 + k);
        const short8 l1 = *(const short8*)(al + arow1 + k);
        const short8 bh = *(const short8*)((const short*)W3h + bcol + k);
        const short8 bl = *(const short8*)((const short*)W3l + bcol + k);
        acc0 = __builtin_amdgcn_mfma_f32_16x16x32_bf16(h0, bh, acc0, 0,0,0);
        acc1 = __builtin_amdgcn_mfma_f32_16x16x32_bf16(h1, bh, acc1, 0,0,0);
        acc0 = __builtin_amdgcn_mfma_f32_16x16x32_bf16(h0, bl, acc0, 0,0,0);
        acc1 = __builtin_amdgcn_mfma_f32_16x16x32_bf16(h1, bl, acc1, 0,0,0);
        acc0 = __builtin_amdgcn_mfma_f32_16x16x32_bf16(l0, bh, acc0, 0,0,0);
        acc1 = __builtin_amdgcn_mfma_f32_16x16x32_bf16(l1, bh, acc1, 0,0,0);
      }
    }
    __shared__ float red[3][32][16];
    if (w > 0){
#pragma unroll
      for (int i2=0;i2<4;++i2){
        red[w-1][(lg<<2)+i2][lr]      = acc0[i2];
        red[w-1][16+(lg<<2)+i2][lr]   = acc1[i2];
      }
    }
    __syncthreads();
    if (w == 0){
      float* __restrict__ C = g2 ? C2 : C1;
#pragma unroll
      for (int i2=0;i2<4;++i2){
        float v0 = acc0[i2], v1 = acc1[i2];
        v0 += red[0][(lg<<2)+i2][lr];  v1 += red[0][16+(lg<<2)+i2][lr];
        v0 += red[1][(lg<<2)+i2][lr];  v1 += red[1][16+(lg<<2)+i2][lr];
        v0 += red[2][(lg<<2)+i2][lr];  v1 += red[2][16+(lg<<2)+i2][lr];
        C[((rb + (lg<<2)+i2) << 10) + cb + lr]      = v0;
        C[((rb + 16 + (lg<<2)+i2) << 10) + cb + lr] = v1;
      }
    }
  } else {
    // s0: 16 rows per block, 16 lanes per row
    const int r    = ((bid - 1024) << 4) + (tid >> 4);
    const int lane = tid & 15;
    float a[10] = {0.f,0.f,0.f,0.f,0.f,0.f,0.f,0.f,0.f,0.f};
    for (int k = lane; k < 1024; k += 16){
      const float sv = sp1[r*1024 + k];
#pragma unroll
      for (int c=0;c<10;c++) a[c] = fmaf(sv, W1[k*10+c], a[c]);
    }
#pragma unroll
    for (int c=0;c<10;c++){
      float v = a[c];
      v += __shfl_xor(v, 1);
      v += __shfl_xor(v, 2);
      v += __shfl_xor(v, 4);
      v += __shfl_xor(v, 8);
      a[c] = v;
    }
    if (lane == 0){
#pragma unroll
      for (int c=0;c<10;c++){
        const float s = s0o[r*10+c];
        float v = s + DTv*(-s + a[c] + b0[c]);
        s0n[r*10+c] = fminf(fmaxf(v,0.f),1.f);
      }
    }
  }
}

// ---------------- finish: epilogue + next-step spikes + bf16 operand emit ----------------
__global__ __launch_bounds__(256) void finish_kernel(
    const float* __restrict__ s1o, const float* __restrict__ s2o,
    const float* __restrict__ C1, const float* __restrict__ C2,
    const float* __restrict__ sp0_old, const float* __restrict__ s0n,
    const float* __restrict__ W1, const float* __restrict__ b2, const float* __restrict__ D2,
    float* __restrict__ s1n, float* __restrict__ s2n,
    float* __restrict__ sp0n, float* __restrict__ sp1n, ushort* __restrict__ sp2b,
    ushort* __restrict__ ah, ushort* __restrict__ al, int tnext)
{
  __shared__ uint32_t K[6];
  if (threadIdx.x == 0) step_keys(tnext, K);
  __syncthreads();
  const int bid = blockIdx.x;
  const int tid = threadIdx.x;
  if (bid < 512){
    const bool L1 = bid < 256;
    const int r = L1 ? bid : bid - 256;
    const int c0 = tid << 2;
    const int e = (r << 10) + c0;
    float val[4];
    if (L1){
      const float4 cc = *(const float4*)&C1[e];
      float sv[10];
#pragma unroll
      for (int k=0;k<10;k++) sv[k] = sp0_old[r*10+k];
      const float4 bb = *(const float4*)&b2[c0];
      const float* bp = (const float*)&bb;
      const float* cp = (const float*)&cc;
#pragma unroll
      for (int j=0;j<4;j++){
        float sm = 0.f;
#pragma unroll
        for (int k=0;k<10;k++) sm = fmaf(sv[k], W1[(c0+j)*10+k], sm);
        val[j] = cp[j] + bp[j] + sm;
      }
    } else {
      const float4 cc = *(const float4*)&C2[e];
      const float4 dd = *(const float4*)&D2[e];
      val[0] = cc.x + dd.x; val[1] = cc.y + dd.y; val[2] = cc.z + dd.z; val[3] = cc.w + dd.w;
    }
    const float4 so = L1 ? *(const float4*)&s1o[e] : *(const float4*)&s2o[e];
    const float* sp_ = (const float*)&so;
    const uint32_t kk0 = L1 ? K[2] : K[4];
    const uint32_t kk1 = L1 ? K[3] : K[5];
    float4 nst; float* np = (float*)&nst;
    float vv[4];
#pragma unroll
    for (int j=0;j<4;j++){
      const float s = sp_[j];
      float v = s + DTv*(-s + val[j]);
      v = fminf(fmaxf(v,0.f),1.f);
      np[j] = v; vv[j] = v;
    }
    if (L1){
      *(float4*)&s1n[e] = nst;
      float4 spk; float* kp = (float*)&spk;
      ushort4 hq, lq; ushort* hp=(ushort*)&hq; ushort* lp=(ushort*)&lq;
#pragma unroll
      for (int j=0;j<4;j++){
        uint32_t x0 = 0u, x1 = (uint32_t)(e + j);
        tf2x32(kk0, kk1, x0, x1);
        kp[j] = (u01(x0 ^ x1) < vv[j]) ? 1.0f : 0.0f;
        hp[j] = f2bf(vv[j]);
        lp[j] = f2bf(vv[j] - bf2f(hp[j]));
      }
      *(float4*)&sp1n[e] = spk;
      *(ushort4*)&ah[e] = hq;
      *(ushort4*)&al[e] = lq;
    } else {
      *(float4*)&s2n[e] = nst;
      ushort4 spk; ushort* kp = (ushort*)&spk;
#pragma unroll
      for (int j=0;j<4;j++){
        uint32_t x0 = 0u, x1 = (uint32_t)(e + j);
        tf2x32(kk0, kk1, x0, x1);
        kp[j] = (u01(x0 ^ x1) < vv[j]) ? (ushort)0x3F80u : (ushort)0u;
      }
      *(ushort4*)&sp2b[e] = spk;
    }
  } else {
    for (int i = tid; i < 2560; i += 256){
      uint32_t x0 = 0u, x1 = (uint32_t)i;
      tf2x32(K[0], K[1], x0, x1);
      sp0n[i] = (u01(x0 ^ x1) < s0n[i]) ? 1.0f : 0.0f;
    }
  }
}

// ---------------- host ----------------
extern "C" void kernel_launch(void* const* d_in, const int* in_sizes, int n_in,
                              void* d_out, int out_size, void* d_ws, size_t ws_size,
                              hipStream_t stream)
{
  const float* data = (const float*)d_in[0];
  const float* s0i  = (const float*)d_in[1];
  const float* s1i  = (const float*)d_in[2];
  const float* s2i  = (const float*)d_in[3];
  const float* b0   = (const float*)d_in[5];
  const float* W1   = (const float*)d_in[6];
  const float* W2   = (const float*)d_in[7];
  const float* b2   = (const float*)d_in[8];
  const float* W3   = (const float*)d_in[9];
  const float* W4   = (const float*)d_in[10];
  const float* b4   = (const float*)d_in[11];
  float* out = (float*)d_out;
  float* ws  = (float*)d_ws;

  // ws layout (floats), ~25.7 MB
  const int SZ = 526848;
  float* S[2][3];
  for (int b = 0; b < 2; ++b){
    float* sb = ws + b*SZ;
    S[b][0]=sb; S[b][1]=sb+2560; S[b][2]=sb+264704;
  }
  float* sp0[2] = { ws + 1053696, ws + 1056256 };
  float* sp1 = ws + 1058816;
  float* D2  = ws + 1320960;
  float* C1  = ws + 1583104;
  float* C2  = ws + 1845248;
  float* Pd2 = ws + 2107392;                 // 7 * 262144
  ushort* sp2b = (ushort*)(ws + 3942400);    // 262144 ushorts
  ushort* ah   = (ushort*)(ws + 4073472);
  ushort* al   = (ushort*)(ws + 4204544);
  ushort* W2h  = (ushort*)(ws + 4335616);    // 1048576 ushorts each
  ushort* W2l  = (ushort*)(ws + 4859904);
  ushort* W3h  = (ushort*)(ws + 5384192);
  ushort* W3l  = (ushort*)(ws + 5908480);

  init_kernel<<<1024,256,0,stream>>>(s0i,s1i,s2i,data, S[0][0],S[0][1],S[0][2], ah, al, out + 526848);
  wsplit_kernel<<<2048,256,0,stream>>>(W2, W3, W2h, W2l, W3h, W3l);
  d2p_kernel<<<448,256,0,stream>>>(data, W4, Pd2);
  d2r_kernel<<<256,256,0,stream>>>(Pd2, b4, D2);
  spike_kernel<<<2058,256,0,stream>>>(S[0][0],S[0][1],S[0][2], sp0[0], sp1, sp2b, 0);
  int cur = 0;
  for (int t = 0; t < 30; ++t){
    const int nxt = cur ^ 1;
    mfma_kernel<<<1040,256,0,stream>>>(
        sp2b, ah, al, W2h, W2l, W3h, W3l,
        S[cur][0], sp1, W1, b0, C1, C2, S[nxt][0]);
    finish_kernel<<<513,256,0,stream>>>(
        S[cur][1], S[cur][2], C1, C2, sp0[cur], S[nxt][0],
        W1, b2, D2, S[nxt][1], S[nxt][2],
        sp0[nxt], sp1, sp2b, ah, al, t+1);
    cur = nxt;
  }
  final_kernel<<<1024,256,0,stream>>>(S[cur][0],S[cur][1],S[cur][2], out);
}

// Round 5
// 1246.302 us; speedup vs baseline: 1.0980x; 1.0980x over previous
//
#include <hip/hip_runtime.h>
#include <stdint.h>

#define DTv 0.2f

typedef __attribute__((ext_vector_type(8))) short short8;
typedef __attribute__((ext_vector_type(4))) float f32x4;

// ---------------- threefry2x32, bit-exact to JAX (partitionable) ----------------
__device__ __forceinline__ uint32_t rotl32(uint32_t v, uint32_t r){ return (v<<r)|(v>>(32u-r)); }

__device__ __forceinline__ void tf2x32(uint32_t k0, uint32_t k1, uint32_t& x0, uint32_t& x1){
  const uint32_t k2 = k0 ^ k1 ^ 0x1BD11BDAu;
  x0 += k0; x1 += k1;
#define RND(r) { x0 += x1; x1 = rotl32(x1,(r)); x1 ^= x0; }
  RND(13u) RND(15u) RND(26u) RND(6u)
  x0 += k1; x1 += k2 + 1u;
  RND(17u) RND(29u) RND(16u) RND(24u)
  x0 += k2; x1 += k0 + 2u;
  RND(13u) RND(15u) RND(26u) RND(6u)
  x0 += k0; x1 += k1 + 3u;
  RND(17u) RND(29u) RND(16u) RND(24u)
  x0 += k1; x1 += k2 + 4u;
  RND(13u) RND(15u) RND(26u) RND(6u)
  x0 += k2; x1 += k0 + 5u;
#undef RND
}

__device__ __forceinline__ float u01(uint32_t bits){
  return __uint_as_float((bits >> 9) | 0x3f800000u) - 1.0f;
}

__device__ inline void step_keys(int t, uint32_t* K){
  uint32_t c0 = 0u, c1 = (uint32_t)t;
  tf2x32(0u, 42u, c0, c1);
#pragma unroll
  for (int i = 0; i < 3; ++i){
    uint32_t a = 0u, b = (uint32_t)i;
    tf2x32(c0, c1, a, b);
    K[2*i] = a; K[2*i+1] = b;
  }
}

// ---------------- bf16 helpers (RNE) ----------------
__device__ __forceinline__ ushort f2bf(float f){
  uint32_t u = __float_as_uint(f);
  u += 0x7fffu + ((u >> 16) & 1u);
  return (ushort)(u >> 16);
}
__device__ __forceinline__ float bf2f(ushort h){ return __uint_as_float(((uint32_t)h) << 16); }

// ---------------- spike generation for t=0 ----------------
__global__ __launch_bounds__(256) void spike_kernel(
    const float* __restrict__ s0, const float* __restrict__ s1, const float* __restrict__ s2,
    float* __restrict__ sp0, float* __restrict__ sp1, ushort* __restrict__ sp2b, int t)
{
  __shared__ uint32_t K[6];
  if (threadIdx.x == 0) step_keys(t, K);
  __syncthreads();
  const int g = blockIdx.x * 256 + threadIdx.x;
  const int E0 = 2560, E1 = E0 + 262144;
  if (g < E0){
    uint32_t x0 = 0u, x1 = (uint32_t)g;
    tf2x32(K[0], K[1], x0, x1);
    const float r = fminf(fmaxf(s0[g], 0.f), 1.f);
    sp0[g] = (u01(x0 ^ x1) < r) ? 1.0f : 0.0f;
  } else if (g < E1){
    const int n = g - E0;
    uint32_t x0 = 0u, x1 = (uint32_t)n;
    tf2x32(K[2], K[3], x0, x1);
    const float r = fminf(fmaxf(s1[n], 0.f), 1.f);
    sp1[n] = (u01(x0 ^ x1) < r) ? 1.0f : 0.0f;
  } else {
    const int n = g - E1;
    uint32_t x0 = 0u, x1 = (uint32_t)n;
    tf2x32(K[4], K[5], x0, x1);
    const float r = fminf(fmaxf(s2[n], 0.f), 1.f);
    sp2b[n] = (u01(x0 ^ x1) < r) ? (ushort)0x3F80u : (ushort)0u;
  }
}

// ---------------- init / final ----------------
__global__ __launch_bounds__(256) void init_kernel(
    const float* __restrict__ s0i, const float* __restrict__ s1i, const float* __restrict__ s2i,
    const float* __restrict__ data,
    float* __restrict__ b0s, float* __restrict__ b1s, float* __restrict__ b2s,
    ushort* __restrict__ ah, ushort* __restrict__ al,
    float* __restrict__ out_data)
{
  const int i = blockIdx.x*256 + threadIdx.x;
  if (i < 2560)   b0s[i] = s0i[i];
  if (i < 262144){
    b1s[i] = s1i[i]; b2s[i] = s2i[i];
    const float v = fminf(fmaxf(s1i[i], 0.f), 1.f);
    const ushort h = f2bf(v);
    ah[i] = h; al[i] = f2bf(v - bf2f(h));
  }
  if (i < 200704) out_data[i] = data[i];
}

__global__ __launch_bounds__(256) void final_kernel(
    const float* __restrict__ b0s, const float* __restrict__ b1s, const float* __restrict__ b2s,
    float* __restrict__ out)
{
  const int i = blockIdx.x*256 + threadIdx.x;
  if (i < 2560)   out[i] = b0s[i];
  if (i < 262144){ out[2560+i] = b1s[i]; out[264704+i] = b2s[i]; }
}

// ---------------- weight split ----------------
__global__ __launch_bounds__(256) void wsplit_kernel(
    const float* __restrict__ W2, const float* __restrict__ W3,
    ushort* __restrict__ W2h, ushort* __restrict__ W2l,
    ushort* __restrict__ W3h, ushort* __restrict__ W3l)
{
  int idx = (blockIdx.x*256 + threadIdx.x) << 2;
  const float* W; ushort *H, *L;
  if (idx < 1048576){ W = W2; H = W2h; L = W2l; }
  else { idx -= 1048576; W = W3; H = W3h; L = W3l; }
  const float4 v = *(const float4*)&W[idx];
  const float* vp = (const float*)&v;
  ushort4 h, l;
  ushort* hp = (ushort*)&h; ushort* lp = (ushort*)&l;
#pragma unroll
  for (int j=0;j<4;j++){
    hp[j] = f2bf(vp[j]);
    lp[j] = f2bf(vp[j] - bf2f(hp[j]));
  }
  *(ushort4*)&H[idx] = h;
  *(ushort4*)&L[idx] = l;
}

// ---------------- D2 = data @ W4^T + b4 (split-K once per launch) ----------------
__global__ __launch_bounds__(256) void d2p_kernel(
    const float* __restrict__ data, const float* __restrict__ W4, float* __restrict__ Pd2)
{
  __shared__ float As[16][64];
  __shared__ float Bs[16][64];
  const int tb = blockIdx.x / 7;
  const int ch = blockIdx.x % 7;
  const int kb = ch * 112;
  const int R0 = (tb >> 4) << 6;
  const int C0 = (tb & 15) << 6;
  const int tid = threadIdx.x;
  const int ty = tid >> 4, tx = tid & 15;
  const int mA = tid >> 2, kqA = (tid & 3) << 2;
  float acc[4][4] = {{0.f}};
  for (int kk = 0; kk < 112; kk += 16){
    const float4 a = *(const float4*)&data[(R0+mA)*784 + kb + kk + kqA];
    As[kqA+0][mA]=a.x; As[kqA+1][mA]=a.y; As[kqA+2][mA]=a.z; As[kqA+3][mA]=a.w;
    const float4 b = *(const float4*)&W4[(C0+mA)*784 + kb + kk + kqA];
    Bs[kqA+0][mA]=b.x; Bs[kqA+1][mA]=b.y; Bs[kqA+2][mA]=b.z; Bs[kqA+3][mA]=b.w;
    __syncthreads();
#pragma unroll
    for (int k=0;k<16;k++){
      const float4 av = *(const float4*)&As[k][ty<<2];
      const float4 bv = *(const float4*)&Bs[k][tx<<2];
      acc[0][0]=fmaf(av.x,bv.x,acc[0][0]); acc[0][1]=fmaf(av.x,bv.y,acc[0][1]);
      acc[0][2]=fmaf(av.x,bv.z,acc[0][2]); acc[0][3]=fmaf(av.x,bv.w,acc[0][3]);
      acc[1][0]=fmaf(av.y,bv.x,acc[1][0]); acc[1][1]=fmaf(av.y,bv.y,acc[1][1]);
      acc[1][2]=fmaf(av.y,bv.z,acc[1][2]); acc[1][3]=fmaf(av.y,bv.w,acc[1][3]);
      acc[2][0]=fmaf(av.z,bv.x,acc[2][0]); acc[2][1]=fmaf(av.z,bv.y,acc[2][1]);
      acc[2][2]=fmaf(av.z,bv.z,acc[2][2]); acc[2][3]=fmaf(av.z,bv.w,acc[2][3]);
      acc[3][0]=fmaf(av.w,bv.x,acc[3][0]); acc[3][1]=fmaf(av.w,bv.y,acc[3][1]);
      acc[3][2]=fmaf(av.w,bv.z,acc[3][2]); acc[3][3]=fmaf(av.w,bv.w,acc[3][3]);
    }
    __syncthreads();
  }
  float* P = Pd2 + ch*262144;
#pragma unroll
  for (int i=0;i<4;i++){
    const int r = R0 + (ty<<2) + i;
    float4 o; float* op=(float*)&o;
#pragma unroll
    for (int j=0;j<4;j++) op[j] = acc[i][j];
    *(float4*)&P[r*1024 + C0 + (tx<<2)] = o;
  }
}

__global__ __launch_bounds__(256) void d2r_kernel(
    const float* __restrict__ Pd2, const float* __restrict__ b4, float* __restrict__ D2)
{
  const int e = (blockIdx.x*256 + threadIdx.x) << 2;
  float4 acc = *(const float4*)&Pd2[e];
#pragma unroll
  for (int p = 1; p < 7; ++p){
    const float4 q = *(const float4*)&Pd2[p*262144 + e];
    acc.x += q.x; acc.y += q.y; acc.z += q.z; acc.w += q.w;
  }
  const float4 bb = *(const float4*)&b4[e & 1023];
  acc.x += bb.x; acc.y += bb.y; acc.z += bb.z; acc.w += bb.w;
  *(float4*)&D2[e] = acc;
}

// ---------------- fully-fused per-step kernel ----------------
// bid 0..15    : s0 rows update (sp1_o @ W1, K=1024) + sp0_n draw
// bid 16..1039 : GEMM tiles 32x16, fused epilogue + spike/operand emission
#define MFMA16(A,B,C) __builtin_amdgcn_mfma_f32_16x16x32_bf16(A,B,C,0,0,0)
__global__ __launch_bounds__(256, 4) void step_kernel(
    const ushort* __restrict__ sp2b_o, const ushort* __restrict__ ah_o, const ushort* __restrict__ al_o,
    const float* __restrict__ sp0_o, const float* __restrict__ sp1_o,
    float* __restrict__ s0s, float* __restrict__ s1s, float* __restrict__ s2s,
    const ushort* __restrict__ W2h, const ushort* __restrict__ W2l,
    const ushort* __restrict__ W3h, const ushort* __restrict__ W3l,
    const float* __restrict__ W1, const float* __restrict__ b0,
    const float* __restrict__ b2, const float* __restrict__ D2,
    float* __restrict__ sp0_n, float* __restrict__ sp1_n, ushort* __restrict__ sp2b_n,
    ushort* __restrict__ ah_n, ushort* __restrict__ al_n,
    int tnext)
{
  __shared__ float red[3][32][16];
  __shared__ uint32_t K[6];
  const int bid = blockIdx.x;
  const int tid = threadIdx.x;
  if (bid >= 16){
    const int gb = bid - 16;
    const int xcd = gb & 7;
    const int ib  = gb >> 3;
    const int coltile = xcd*8 + (ib & 7);
    const int rowtile = (ib >> 3) & 7;
    const int g2      = (ib >> 6) & 1;
    const int lane = tid & 63;
    const int w    = tid >> 6;
    const int rb = rowtile << 5, cb = coltile << 4;
    const int lr = lane & 15, lg = lane >> 4;
    const int arow0 = (rb + lr) << 10;
    const int arow1 = arow0 + (16 << 10);
    const int bcol  = (cb + lr) << 10;
    const int k0    = (w << 8) + (lg << 3);
    f32x4 acc0 = {0.f,0.f,0.f,0.f}, acc1 = {0.f,0.f,0.f,0.f};
    if (g2 == 0){
      const short* Bh = (const short*)W2h + bcol;
      const short* Bl = (const short*)W2l + bcol;
      short8 a0A,a1A,bhA,blA, a0B,a1B,bhB,blB;
#define LD1(ks,a0,a1,bh,bl) { const int k = k0 + ((ks)<<5); \
      a0 = *(const short8*)((const short*)sp2b_o + arow0 + k); \
      a1 = *(const short8*)((const short*)sp2b_o + arow1 + k); \
      bh = *(const short8*)(Bh + k); bl = *(const short8*)(Bl + k); }
      LD1(0, a0A,a1A,bhA,blA)
#pragma unroll
      for (int ks = 0; ks < 8; ++ks){
        if ((ks & 1) == 0){
          if (ks < 7) LD1(ks+1, a0B,a1B,bhB,blB)
          acc0 = MFMA16(a0A,bhA,acc0); acc1 = MFMA16(a1A,bhA,acc1);
          acc0 = MFMA16(a0A,blA,acc0); acc1 = MFMA16(a1A,blA,acc1);
        } else {
          if (ks < 7) LD1(ks+1, a0A,a1A,bhA,blA)
          acc0 = MFMA16(a0B,bhB,acc0); acc1 = MFMA16(a1B,bhB,acc1);
          acc0 = MFMA16(a0B,blB,acc0); acc1 = MFMA16(a1B,blB,acc1);
        }
      }
#undef LD1
    } else {
      const short* Bh = (const short*)W3h + bcol;
      const short* Bl = (const short*)W3l + bcol;
      short8 h0A,h1A,l0A,l1A,bhA,blA, h0B,h1B,l0B,l1B,bhB,blB;
#define LD2(ks,h0,h1,l0,l1,bh,bl) { const int k = k0 + ((ks)<<5); \
      h0 = *(const short8*)((const short*)ah_o + arow0 + k); \
      h1 = *(const short8*)((const short*)ah_o + arow1 + k); \
      l0 = *(const short8*)((const short*)al_o + arow0 + k); \
      l1 = *(const short8*)((const short*)al_o + arow1 + k); \
      bh = *(const short8*)(Bh + k); bl = *(const short8*)(Bl + k); }
      LD2(0, h0A,h1A,l0A,l1A,bhA,blA)
#pragma unroll
      for (int ks = 0; ks < 8; ++ks){
        if ((ks & 1) == 0){
          if (ks < 7) LD2(ks+1, h0B,h1B,l0B,l1B,bhB,blB)
          acc0 = MFMA16(h0A,bhA,acc0); acc1 = MFMA16(h1A,bhA,acc1);
          acc0 = MFMA16(h0A,blA,acc0); acc1 = MFMA16(h1A,blA,acc1);
          acc0 = MFMA16(l0A,bhA,acc0); acc1 = MFMA16(l1A,bhA,acc1);
        } else {
          if (ks < 7) LD2(ks+1, h0A,h1A,l0A,l1A,bhA,blA)
          acc0 = MFMA16(h0B,bhB,acc0); acc1 = MFMA16(h1B,bhB,acc1);
          acc0 = MFMA16(h0B,blB,acc0); acc1 = MFMA16(h1B,blB,acc1);
          acc0 = MFMA16(l0B,bhB,acc0); acc1 = MFMA16(l1B,bhB,acc1);
        }
      }
#undef LD2
    }
    if (w > 0){
#pragma unroll
      for (int i2=0;i2<4;++i2){
        red[w-1][(lg<<2)+i2][lr]    = acc0[i2];
        red[w-1][16+(lg<<2)+i2][lr] = acc1[i2];
      }
    }
    if (tid == 0) step_keys(tnext, K);
    __syncthreads();
    if (w == 0){
      const uint32_t kk0 = g2 ? K[4] : K[2];
      const uint32_t kk1 = g2 ? K[5] : K[3];
      const int c = cb + lr;
#pragma unroll
      for (int i2=0;i2<4;++i2){
        const int r0 = rb + (lg<<2) + i2;
        const int r1 = r0 + 16;
        float v0 = acc0[i2], v1 = acc1[i2];
        v0 += red[0][(lg<<2)+i2][lr];    v1 += red[0][16+(lg<<2)+i2][lr];
        v0 += red[1][(lg<<2)+i2][lr];    v1 += red[1][16+(lg<<2)+i2][lr];
        v0 += red[2][(lg<<2)+i2][lr];    v1 += red[2][16+(lg<<2)+i2][lr];
        const int e0 = (r0<<10) + c, e1 = (r1<<10) + c;
        if (g2 == 0){
          float sm0 = 0.f, sm1 = 0.f;
#pragma unroll
          for (int k2=0;k2<10;k2++){
            const float wv = W1[c*10+k2];
            sm0 = fmaf(sp0_o[r0*10+k2], wv, sm0);
            sm1 = fmaf(sp0_o[r1*10+k2], wv, sm1);
          }
          const float bv = b2[c];
          v0 = v0 + bv + sm0;
          v1 = v1 + bv + sm1;
          {
            const float s = s1s[e0];
            float v = s + DTv*(-s + v0);
            v = fminf(fmaxf(v,0.f),1.f);
            s1s[e0] = v;
            uint32_t x0=0u, x1=(uint32_t)e0; tf2x32(kk0,kk1,x0,x1);
            sp1_n[e0] = (u01(x0^x1) < v) ? 1.0f : 0.0f;
            const ushort hh = f2bf(v);
            ah_n[e0] = hh; al_n[e0] = f2bf(v - bf2f(hh));
          }
          {
            const float s = s1s[e1];
            float v = s + DTv*(-s + v1);
            v = fminf(fmaxf(v,0.f),1.f);
            s1s[e1] = v;
            uint32_t x0=0u, x1=(uint32_t)e1; tf2x32(kk0,kk1,x0,x1);
            sp1_n[e1] = (u01(x0^x1) < v) ? 1.0f : 0.0f;
            const ushort hh = f2bf(v);
            ah_n[e1] = hh; al_n[e1] = f2bf(v - bf2f(hh));
          }
        } else {
          v0 += D2[e0];
          v1 += D2[e1];
          {
            const float s = s2s[e0];
            float v = s + DTv*(-s + v0);
            v = fminf(fmaxf(v,0.f),1.f);
            s2s[e0] = v;
            uint32_t x0=0u, x1=(uint32_t)e0; tf2x32(kk0,kk1,x0,x1);
            sp2b_n[e0] = (u01(x0^x1) < v) ? (ushort)0x3F80u : (ushort)0u;
          }
          {
            const float s = s2s[e1];
            float v = s + DTv*(-s + v1);
            v = fminf(fmaxf(v,0.f),1.f);
            s2s[e1] = v;
            uint32_t x0=0u, x1=(uint32_t)e1; tf2x32(kk0,kk1,x0,x1);
            sp2b_n[e1] = (u01(x0^x1) < v) ? (ushort)0x3F80u : (ushort)0u;
          }
        }
      }
    }
  } else {
    // s0 blocks: 16 rows each
    if (tid == 0) step_keys(tnext, K);
    const int r    = (bid << 4) + (tid >> 4);
    const int lane = tid & 15;
    float a[10] = {0.f,0.f,0.f,0.f,0.f,0.f,0.f,0.f,0.f,0.f};
    for (int k = lane; k < 1024; k += 16){
      const float sv = sp1_o[(r<<10) + k];
#pragma unroll
      for (int c=0;c<10;c++) a[c] = fmaf(sv, W1[k*10+c], a[c]);
    }
#pragma unroll
    for (int c=0;c<10;c++){
      float v = a[c];
      v += __shfl_xor(v, 1);
      v += __shfl_xor(v, 2);
      v += __shfl_xor(v, 4);
      v += __shfl_xor(v, 8);
      a[c] = v;
    }
    __syncthreads();
    if (lane == 0){
#pragma unroll
      for (int c=0;c<10;c++){
        const float s = s0s[r*10+c];
        float v = s + DTv*(-s + a[c] + b0[c]);
        v = fminf(fmaxf(v,0.f),1.f);
        s0s[r*10+c] = v;
        uint32_t x0=0u, x1=(uint32_t)(r*10+c); tf2x32(K[0],K[1],x0,x1);
        sp0_n[r*10+c] = (u01(x0^x1) < v) ? 1.0f : 0.0f;
      }
    }
  }
}

// ---------------- host ----------------
extern "C" void kernel_launch(void* const* d_in, const int* in_sizes, int n_in,
                              void* d_out, int out_size, void* d_ws, size_t ws_size,
                              hipStream_t stream)
{
  const float* data = (const float*)d_in[0];
  const float* s0i  = (const float*)d_in[1];
  const float* s1i  = (const float*)d_in[2];
  const float* s2i  = (const float*)d_in[3];
  const float* b0   = (const float*)d_in[5];
  const float* W1   = (const float*)d_in[6];
  const float* W2   = (const float*)d_in[7];
  const float* b2   = (const float*)d_in[8];
  const float* W3   = (const float*)d_in[9];
  const float* W4   = (const float*)d_in[10];
  const float* b4   = (const float*)d_in[11];
  float* out = (float*)d_out;
  float* ws  = (float*)d_ws;

  // ws layout (float offsets)
  float* s0s = ws + 0;            // 2560
  float* s1s = ws + 2560;         // 262144
  float* s2s = ws + 264704;       // 262144
  float* sp0[2] = { ws + 526848, ws + 529408 };     // 2x2560
  float* sp1[2] = { ws + 531968, ws + 794112 };     // 2x262144
  float* D2  = ws + 1056256;      // 262144
  float* Pd2 = ws + 1318400;      // 7*262144 = 1835008
  ushort* sp2b[2] = { (ushort*)(ws + 3153408), (ushort*)(ws + 3284480) };
  ushort* ah[2]   = { (ushort*)(ws + 3415552), (ushort*)(ws + 3546624) };
  ushort* al[2]   = { (ushort*)(ws + 3677696), (ushort*)(ws + 3808768) };
  ushort* W2h = (ushort*)(ws + 3939840);
  ushort* W2l = (ushort*)(ws + 4464128);
  ushort* W3h = (ushort*)(ws + 4988416);
  ushort* W3l = (ushort*)(ws + 5512704);

  init_kernel<<<1024,256,0,stream>>>(s0i,s1i,s2i,data, s0s,s1s,s2s, ah[0], al[0], out + 526848);
  wsplit_kernel<<<2048,256,0,stream>>>(W2, W3, W2h, W2l, W3h, W3l);
  d2p_kernel<<<448,256,0,stream>>>(data, W4, Pd2);
  d2r_kernel<<<256,256,0,stream>>>(Pd2, b4, D2);
  spike_kernel<<<2058,256,0,stream>>>(s0s,s1s,s2s, sp0[0], sp1[0], sp2b[0], 0);
  for (int t = 0; t < 30; ++t){
    const int cur = t & 1, nxt = cur ^ 1;
    step_kernel<<<1040,256,0,stream>>>(
        sp2b[cur], ah[cur], al[cur], sp0[cur], sp1[cur],
        s0s, s1s, s2s,
        W2h, W2l, W3h, W3l, W1, b0, b2, D2,
        sp0[nxt], sp1[nxt], sp2b[nxt], ah[nxt], al[nxt],
        t+1);
  }
  final_kernel<<<1024,256,0,stream>>>(s0s, s1s, s2s, out);
}

// Round 6
// 1134.054 us; speedup vs baseline: 1.2067x; 1.0990x over previous
//
#include <hip/hip_runtime.h>
#include <stdint.h>

#define DTv 0.2f

typedef __attribute__((ext_vector_type(8))) short short8;
typedef __attribute__((ext_vector_type(4))) float f32x4;
#define MFMA16(A,B,C) __builtin_amdgcn_mfma_f32_16x16x32_bf16(A,B,C,0,0,0)

// ---------------- threefry2x32, bit-exact to JAX (partitionable) ----------------
__device__ __forceinline__ uint32_t rotl32(uint32_t v, uint32_t r){ return (v<<r)|(v>>(32u-r)); }

__device__ __forceinline__ void tf2x32(uint32_t k0, uint32_t k1, uint32_t& x0, uint32_t& x1){
  const uint32_t k2 = k0 ^ k1 ^ 0x1BD11BDAu;
  x0 += k0; x1 += k1;
#define RND(r) { x0 += x1; x1 = rotl32(x1,(r)); x1 ^= x0; }
  RND(13u) RND(15u) RND(26u) RND(6u)
  x0 += k1; x1 += k2 + 1u;
  RND(17u) RND(29u) RND(16u) RND(24u)
  x0 += k2; x1 += k0 + 2u;
  RND(13u) RND(15u) RND(26u) RND(6u)
  x0 += k0; x1 += k1 + 3u;
  RND(17u) RND(29u) RND(16u) RND(24u)
  x0 += k1; x1 += k2 + 4u;
  RND(13u) RND(15u) RND(26u) RND(6u)
  x0 += k2; x1 += k0 + 5u;
#undef RND
}

__device__ __forceinline__ float u01(uint32_t bits){
  return __uint_as_float((bits >> 9) | 0x3f800000u) - 1.0f;
}

__device__ __forceinline__ void step_keys(int t, uint32_t* K){
  uint32_t c0 = 0u, c1 = (uint32_t)t;
  tf2x32(0u, 42u, c0, c1);
#pragma unroll
  for (int i = 0; i < 3; ++i){
    uint32_t a = 0u, b = (uint32_t)i;
    tf2x32(c0, c1, a, b);
    K[2*i] = a; K[2*i+1] = b;
  }
}

// ---------------- bf16 helpers (RNE) ----------------
__device__ __forceinline__ ushort f2bf(float f){
  uint32_t u = __float_as_uint(f);
  u += 0x7fffu + ((u >> 16) & 1u);
  return (ushort)(u >> 16);
}
__device__ __forceinline__ float bf2f(ushort h){ return __uint_as_float(((uint32_t)h) << 16); }

// ---------------- D2 = data @ W4^T + b4 (once per launch) ----------------
__global__ __launch_bounds__(256) void d2p_kernel(
    const float* __restrict__ data, const float* __restrict__ W4, float* __restrict__ Pd2)
{
  __shared__ float As[16][64];
  __shared__ float Bs[16][64];
  const int tb = blockIdx.x / 7;
  const int ch = blockIdx.x % 7;
  const int kb = ch * 112;
  const int R0 = (tb >> 4) << 6;
  const int C0 = (tb & 15) << 6;
  const int tid = threadIdx.x;
  const int ty = tid >> 4, tx = tid & 15;
  const int mA = tid >> 2, kqA = (tid & 3) << 2;
  float acc[4][4] = {{0.f}};
  for (int kk = 0; kk < 112; kk += 16){
    const float4 a = *(const float4*)&data[(R0+mA)*784 + kb + kk + kqA];
    As[kqA+0][mA]=a.x; As[kqA+1][mA]=a.y; As[kqA+2][mA]=a.z; As[kqA+3][mA]=a.w;
    const float4 b = *(const float4*)&W4[(C0+mA)*784 + kb + kk + kqA];
    Bs[kqA+0][mA]=b.x; Bs[kqA+1][mA]=b.y; Bs[kqA+2][mA]=b.z; Bs[kqA+3][mA]=b.w;
    __syncthreads();
#pragma unroll
    for (int k=0;k<16;k++){
      const float4 av = *(const float4*)&As[k][ty<<2];
      const float4 bv = *(const float4*)&Bs[k][tx<<2];
      acc[0][0]=fmaf(av.x,bv.x,acc[0][0]); acc[0][1]=fmaf(av.x,bv.y,acc[0][1]);
      acc[0][2]=fmaf(av.x,bv.z,acc[0][2]); acc[0][3]=fmaf(av.x,bv.w,acc[0][3]);
      acc[1][0]=fmaf(av.y,bv.x,acc[1][0]); acc[1][1]=fmaf(av.y,bv.y,acc[1][1]);
      acc[1][2]=fmaf(av.y,bv.z,acc[1][2]); acc[1][3]=fmaf(av.y,bv.w,acc[1][3]);
      acc[2][0]=fmaf(av.z,bv.x,acc[2][0]); acc[2][1]=fmaf(av.z,bv.y,acc[2][1]);
      acc[2][2]=fmaf(av.z,bv.z,acc[2][2]); acc[2][3]=fmaf(av.z,bv.w,acc[2][3]);
      acc[3][0]=fmaf(av.w,bv.x,acc[3][0]); acc[3][1]=fmaf(av.w,bv.y,acc[3][1]);
      acc[3][2]=fmaf(av.w,bv.z,acc[3][2]); acc[3][3]=fmaf(av.w,bv.w,acc[3][3]);
    }
    __syncthreads();
  }
  float* P = Pd2 + ch*262144;
#pragma unroll
  for (int i=0;i<4;i++){
    const int r = R0 + (ty<<2) + i;
    float4 o; float* op=(float*)&o;
#pragma unroll
    for (int j=0;j<4;j++) op[j] = acc[i][j];
    *(float4*)&P[r*1024 + C0 + (tx<<2)] = o;
  }
}

__global__ __launch_bounds__(256) void d2r_kernel(
    const float* __restrict__ Pd2, const float* __restrict__ b4, float* __restrict__ D2)
{
  const int e = (blockIdx.x*256 + threadIdx.x) << 2;
  float4 acc = *(const float4*)&Pd2[e];
#pragma unroll
  for (int p = 1; p < 7; ++p){
    const float4 q = *(const float4*)&Pd2[p*262144 + e];
    acc.x += q.x; acc.y += q.y; acc.z += q.z; acc.w += q.w;
  }
  const float4 bb = *(const float4*)&b4[e & 1023];
  acc.x += bb.x; acc.y += bb.y; acc.z += bb.z; acc.w += bb.w;
  *(float4*)&D2[e] = acc;
}

// ---------------- grid barrier (agent scope, sense via phase counting) ----------------
__device__ __forceinline__ void gbar(unsigned* bar, unsigned target){
  __syncthreads();
  if (threadIdx.x == 0){
    __hip_atomic_fetch_add(bar, 1u, __ATOMIC_RELEASE, __HIP_MEMORY_SCOPE_AGENT);
    unsigned it = 0;
    while (__hip_atomic_load(bar, __ATOMIC_ACQUIRE, __HIP_MEMORY_SCOPE_AGENT) < target){
      __builtin_amdgcn_s_sleep(4);
      if (++it > (1u<<26)) break;   // safety valve: broken co-residency -> garbage, not hang
    }
  }
  __syncthreads();
}

// ---------------- persistent kernel: all 30 steps ----------------
// 256 blocks (1/CU), 4 waves. Block b: unit=b>>1 (g2=unit>>6, coltile=unit&63), sub=b&1.
// LDS: B-slice (hi/lo bf16, 64KB), W1 (40KB), state slice (8KB), AUX (D2 slice or sp0 slice, 8KB), misc.
// Wave w owns rowtile rt=sub*4+w (32 rows x 16 cols output), full K=1024.
__global__ __launch_bounds__(256) void persist_kernel(
    const float* __restrict__ data, const float* __restrict__ s0i,
    const float* __restrict__ s1i, const float* __restrict__ s2i,
    const float* __restrict__ W1g, const float* __restrict__ W2,
    const float* __restrict__ W3, const float* __restrict__ b0g,
    const float* __restrict__ b2g, const float* __restrict__ D2,
    float* __restrict__ sp0A, float* __restrict__ sp0B,
    float* __restrict__ sp1A, float* __restrict__ sp1B,
    ushort* __restrict__ sp2A, ushort* __restrict__ sp2B,
    ushort* __restrict__ ahA, ushort* __restrict__ ahB,
    ushort* __restrict__ alA, ushort* __restrict__ alB,
    float* __restrict__ out, unsigned* __restrict__ bar)
{
  extern __shared__ char lds[];
  short* Bh   = (short*)lds;                 // 16384 shorts, [kg(128)][col(16)][8]
  short* Bl   = (short*)(lds + 32768);
  float* W1L  = (float*)(lds + 65536);       // 10240 floats, [1024][10]
  float* Sst  = (float*)(lds + 106496);      // 2048 floats, [128][16]
  float* AUX  = (float*)(lds + 114688);      // g2=1: D2 slice [128][16]; g2=0: sp0 slice [128][10]
  float* MISC = (float*)(lds + 122880);
  uint32_t* K = (uint32_t*)MISC;             // 6
  float* b0s   = MISC + 6;                   // 10
  float* s0st  = MISC + 16;                  // 10
  float* s0red = MISC + 26;                  // 40
  float* b2s   = MISC + 66;                  // 16

  const int bid = blockIdx.x, tid = threadIdx.x;
  const int unit = bid >> 1, sub = bid & 1;
  const int g2 = unit >> 6, coltile = unit & 63, cb = coltile << 4;
  const int w = tid >> 6, lane = tid & 63, lr = lane & 15, lg = lane >> 4;

  // ======== pre-loop: fill LDS ========
  { // B slice: rows cb..cb+15 of (g2 ? W3 : W2), split hi/lo
    const float* Wsrc = g2 ? W3 : W2;
    const int row = tid >> 4, seg = tid & 15;
    const float* src = &Wsrc[(cb + row)*1024 + seg*64];
    for (int g = 0; g < 8; ++g){
      short8 h8, l8;
#pragma unroll
      for (int j = 0; j < 8; ++j){
        const float f = src[g*8 + j];
        const ushort hh = f2bf(f);
        h8[j] = (short)hh;
        l8[j] = (short)f2bf(f - bf2f(hh));
      }
      const int kg = seg*8 + g;
      *(short8*)&Bh[(kg*16 + row)*8] = h8;
      *(short8*)&Bl[(kg*16 + row)*8] = l8;
    }
  }
  for (int idx = tid; idx < 10240; idx += 256) W1L[idx] = W1g[idx];
  { // state slice + D2 slice
    const float* Ssrc = g2 ? s2i : s1i;
    for (int idx = tid; idx < 2048; idx += 256){
      const int r = idx >> 4, c = idx & 15;
      Sst[idx] = Ssrc[(((sub<<7) + r) << 10) + cb + c];
    }
    if (g2){
      for (int idx = tid; idx < 2048; idx += 256){
        const int r = idx >> 4, c = idx & 15;
        AUX[idx] = D2[(((sub<<7) + r) << 10) + cb + c];
      }
    }
  }
  if (tid < 10){ b0s[tid] = b0g[tid]; s0st[tid] = s0i[bid*10 + tid]; }
  if (tid < 16) b2s[tid] = b2g[cb + tid];
  for (int idx = tid; idx < 784; idx += 256)
    out[526848 + bid*784 + idx] = data[bid*784 + idx];
  if (tid == 0) step_keys(0, K);
  __syncthreads();

  // spikes(0)
  {
    const uint32_t kk0 = g2 ? K[4] : K[2];
    const uint32_t kk1 = g2 ? K[5] : K[3];
    for (int idx = tid; idx < 2048; idx += 256){
      const int r = (sub<<7) + (idx >> 4);
      const int c = cb + (idx & 15);
      const int e = (r << 10) + c;
      const float v = fminf(fmaxf(Sst[idx], 0.f), 1.f);
      uint32_t x0 = 0u, x1 = (uint32_t)e;
      tf2x32(kk0, kk1, x0, x1);
      const bool sp = (u01(x0 ^ x1) < v);
      if (!g2){
        sp1A[e] = sp ? 1.0f : 0.0f;
        const ushort hh = f2bf(v);
        ahA[e] = hh; alA[e] = f2bf(v - bf2f(hh));
      } else {
        sp2A[e] = sp ? (ushort)0x3F80u : (ushort)0u;
      }
    }
    if (tid < 10){
      const float v = fminf(fmaxf(s0st[tid], 0.f), 1.f);
      const int e = bid*10 + tid;
      uint32_t x0 = 0u, x1 = (uint32_t)e;
      tf2x32(K[0], K[1], x0, x1);
      sp0A[e] = (u01(x0 ^ x1) < v) ? 1.0f : 0.0f;
    }
  }
  unsigned phase = 1;
  gbar(bar, 256u*phase); phase++;

  // ======== 30 steps ========
  const int rt = (sub << 2) + w, rb = rt << 5;
  const int arow0 = (rb + lr) << 10;
  const int arow1 = arow0 + (16 << 10);

#pragma unroll 1
  for (int t = 0; t < 30; ++t){
    const int cur = t & 1;
    const float*  sp0c = cur ? sp0B : sp0A;  float*  sp0n = cur ? sp0A : sp0B;
    const float*  sp1c = cur ? sp1B : sp1A;  float*  sp1n = cur ? sp1A : sp1B;
    const ushort* sp2c = cur ? sp2B : sp2A;  ushort* sp2n = cur ? sp2A : sp2B;
    const ushort* ahc  = cur ? ahB  : ahA;   ushort* ahn  = cur ? ahA  : ahB;
    const ushort* alc  = cur ? alB  : alA;   ushort* aln  = cur ? alA  : alB;

    if (tid == 0) step_keys(t+1, K);
    if (!g2){
      for (int idx = tid; idx < 1280; idx += 256) AUX[idx] = sp0c[sub*1280 + idx];
    }
    __syncthreads();

    // ---- s0 duty: row r = bid (all 256 threads) ----
    {
      float a0_[10] = {0.f,0.f,0.f,0.f,0.f,0.f,0.f,0.f,0.f,0.f};
      const float* sp1r = sp1c + (bid << 10);
#pragma unroll
      for (int q = 0; q < 4; ++q){
        const int k = (q << 8) + tid;
        const float sv = sp1r[k];
        const float* w1k = &W1L[k*10];
#pragma unroll
        for (int c = 0; c < 10; ++c) a0_[c] = fmaf(sv, w1k[c], a0_[c]);
      }
#pragma unroll
      for (int c = 0; c < 10; ++c){
        float v = a0_[c];
        v += __shfl_xor(v, 1);  v += __shfl_xor(v, 2);  v += __shfl_xor(v, 4);
        v += __shfl_xor(v, 8);  v += __shfl_xor(v, 16); v += __shfl_xor(v, 32);
        a0_[c] = v;
      }
      if (lane == 0){
#pragma unroll
        for (int c = 0; c < 10; ++c) s0red[w*10 + c] = a0_[c];
      }
      __syncthreads();
      if (tid < 10){
        const float sum = s0red[tid] + s0red[10+tid] + s0red[20+tid] + s0red[30+tid];
        const float s = s0st[tid];
        float nv = s + DTv*(-s + sum + b0s[tid]);
        nv = fminf(fmaxf(nv, 0.f), 1.f);
        s0st[tid] = nv;
        const int e = bid*10 + tid;
        uint32_t x0 = 0u, x1 = (uint32_t)e;
        tf2x32(K[0], K[1], x0, x1);
        sp0n[e] = (u01(x0 ^ x1) < nv) ? 1.0f : 0.0f;
      }
    }

    // ---- GEMM: wave-owned 32x16 tile, full K ----
    f32x4 acc0 = {0.f,0.f,0.f,0.f}, acc1 = {0.f,0.f,0.f,0.f};
    if (g2 == 0){
      const short* A = (const short*)sp2c;
#pragma unroll 4
      for (int ks = 0; ks < 32; ++ks){
        const int k = (ks << 5) + (lg << 3);
        const short8 a0 = *(const short8*)(A + arow0 + k);
        const short8 a1 = *(const short8*)(A + arow1 + k);
        const int bo = (((ks << 2) + lg)*16 + lr) << 3;
        const short8 bh = *(const short8*)(Bh + bo);
        const short8 bl = *(const short8*)(Bl + bo);
        acc0 = MFMA16(a0, bh, acc0); acc1 = MFMA16(a1, bh, acc1);
        acc0 = MFMA16(a0, bl, acc0); acc1 = MFMA16(a1, bl, acc1);
      }
    } else {
      const short* Ah = (const short*)ahc;
      const short* Al = (const short*)alc;
#pragma unroll 4
      for (int ks = 0; ks < 32; ++ks){
        const int k = (ks << 5) + (lg << 3);
        const short8 h0 = *(const short8*)(Ah + arow0 + k);
        const short8 h1 = *(const short8*)(Ah + arow1 + k);
        const short8 l0 = *(const short8*)(Al + arow0 + k);
        const short8 l1 = *(const short8*)(Al + arow1 + k);
        const int bo = (((ks << 2) + lg)*16 + lr) << 3;
        const short8 bh = *(const short8*)(Bh + bo);
        const short8 bl = *(const short8*)(Bl + bo);
        acc0 = MFMA16(h0, bh, acc0); acc1 = MFMA16(h1, bh, acc1);
        acc0 = MFMA16(h0, bl, acc0); acc1 = MFMA16(h1, bl, acc1);
        acc0 = MFMA16(l0, bh, acc0); acc1 = MFMA16(l1, bh, acc1);
      }
    }

    // ---- epilogue (per wave, per lane: 8 outputs) ----
    {
      const uint32_t kk0 = g2 ? K[4] : K[2];
      const uint32_t kk1 = g2 ? K[5] : K[3];
      const int c = cb + lr;
#pragma unroll
      for (int i2 = 0; i2 < 4; ++i2){
#pragma unroll
        for (int half = 0; half < 2; ++half){
          const int rloc = rb - (sub << 7) + (lg << 2) + i2 + (half << 4);
          float v = half ? acc1[i2] : acc0[i2];
          const int r = (sub << 7) + rloc;
          const int e = (r << 10) + c;
          if (!g2){
            float sm = 0.f;
            const float* w1r = &W1L[c*10];
            const float* sp0r = &AUX[rloc*10];
#pragma unroll
            for (int k2 = 0; k2 < 10; ++k2) sm = fmaf(sp0r[k2], w1r[k2], sm);
            v += b2s[lr] + sm;
          } else {
            v += AUX[(rloc << 4) + lr];
          }
          const float s = Sst[(rloc << 4) + lr];
          float nv = s + DTv*(-s + v);
          nv = fminf(fmaxf(nv, 0.f), 1.f);
          Sst[(rloc << 4) + lr] = nv;
          uint32_t x0 = 0u, x1 = (uint32_t)e;
          tf2x32(kk0, kk1, x0, x1);
          const bool sp = (u01(x0 ^ x1) < nv);
          if (!g2){
            sp1n[e] = sp ? 1.0f : 0.0f;
            const ushort hh = f2bf(nv);
            ahn[e] = hh; aln[e] = f2bf(nv - bf2f(hh));
          } else {
            sp2n[e] = sp ? (ushort)0x3F80u : (ushort)0u;
          }
        }
      }
    }

    if (t < 29){ gbar(bar, 256u*phase); phase++; }
  }

  // ======== write outputs ========
  __syncthreads();
  for (int idx = tid; idx < 2048; idx += 256){
    const int r = (sub << 7) + (idx >> 4);
    const int c = cb + (idx & 15);
    const int e = (r << 10) + c;
    out[(g2 ? 264704 : 2560) + e] = Sst[idx];
  }
  if (tid < 10) out[bid*10 + tid] = s0st[tid];
}

// ---------------- host ----------------
extern "C" void kernel_launch(void* const* d_in, const int* in_sizes, int n_in,
                              void* d_out, int out_size, void* d_ws, size_t ws_size,
                              hipStream_t stream)
{
  const float* data = (const float*)d_in[0];
  const float* s0i  = (const float*)d_in[1];
  const float* s1i  = (const float*)d_in[2];
  const float* s2i  = (const float*)d_in[3];
  const float* b0   = (const float*)d_in[5];
  const float* W1   = (const float*)d_in[6];
  const float* W2   = (const float*)d_in[7];
  const float* b2   = (const float*)d_in[8];
  const float* W3   = (const float*)d_in[9];
  const float* W4   = (const float*)d_in[10];
  const float* b4   = (const float*)d_in[11];
  float* out = (float*)d_out;
  float* ws  = (float*)d_ws;

  // ws layout (float offsets), ~13.7 MB
  float* sp0A = ws + 0;         // 2560
  float* sp0B = ws + 2560;      // 2560
  float* sp1A = ws + 5120;      // 262144
  float* sp1B = ws + 267264;    // 262144
  float* D2   = ws + 529408;    // 262144
  float* Pd2  = ws + 791552;    // 1835008
  ushort* sp2A = (ushort*)(ws + 2626560);  // 262144 ushorts
  ushort* sp2B = (ushort*)(ws + 2757632);
  ushort* ahA  = (ushort*)(ws + 2888704);
  ushort* ahB  = (ushort*)(ws + 3019776);
  ushort* alA  = (ushort*)(ws + 3150848);
  ushort* alB  = (ushort*)(ws + 3281920);
  unsigned* bar = (unsigned*)(ws + 3412992);

  hipMemsetAsync(bar, 0, 64, stream);
  d2p_kernel<<<448,256,0,stream>>>(data, W4, Pd2);
  d2r_kernel<<<256,256,0,stream>>>(Pd2, b4, D2);
  persist_kernel<<<256,256,123264,stream>>>(
      data, s0i, s1i, s2i, W1, W2, W3, b0, b2, D2,
      sp0A, sp0B, sp1A, sp1B, sp2A, sp2B, ahA, ahB, alA, alB,
      out, bar);
}

// Round 7
// 751.701 us; speedup vs baseline: 1.8205x; 1.5087x over previous
//
#include <hip/hip_runtime.h>
#include <stdint.h>

#define DTv 0.2f

typedef __attribute__((ext_vector_type(8))) short short8;
typedef __attribute__((ext_vector_type(4))) float f32x4;
#define MFMA16(A,B,C) __builtin_amdgcn_mfma_f32_16x16x32_bf16(A,B,C,0,0,0)
#define GLOAD16(gp, lp) __builtin_amdgcn_global_load_lds( \
    (const __attribute__((address_space(1))) void*)(gp), \
    (__attribute__((address_space(3))) void*)(lp), 16, 0, 0)

// ---------------- threefry2x32, bit-exact to JAX (partitionable) ----------------
__device__ __forceinline__ uint32_t rotl32(uint32_t v, uint32_t r){ return (v<<r)|(v>>(32u-r)); }

__device__ __forceinline__ void tf2x32(uint32_t k0, uint32_t k1, uint32_t& x0, uint32_t& x1){
  const uint32_t k2 = k0 ^ k1 ^ 0x1BD11BDAu;
  x0 += k0; x1 += k1;
#define RND(r) { x0 += x1; x1 = rotl32(x1,(r)); x1 ^= x0; }
  RND(13u) RND(15u) RND(26u) RND(6u)
  x0 += k1; x1 += k2 + 1u;
  RND(17u) RND(29u) RND(16u) RND(24u)
  x0 += k2; x1 += k0 + 2u;
  RND(13u) RND(15u) RND(26u) RND(6u)
  x0 += k0; x1 += k1 + 3u;
  RND(17u) RND(29u) RND(16u) RND(24u)
  x0 += k1; x1 += k2 + 4u;
  RND(13u) RND(15u) RND(26u) RND(6u)
  x0 += k2; x1 += k0 + 5u;
#undef RND
}

__device__ __forceinline__ float u01(uint32_t bits){
  return __uint_as_float((bits >> 9) | 0x3f800000u) - 1.0f;
}

__device__ __forceinline__ void step_keys(int t, uint32_t* K){
  uint32_t c0 = 0u, c1 = (uint32_t)t;
  tf2x32(0u, 42u, c0, c1);
#pragma unroll
  for (int i = 0; i < 3; ++i){
    uint32_t a = 0u, b = (uint32_t)i;
    tf2x32(c0, c1, a, b);
    K[2*i] = a; K[2*i+1] = b;
  }
}

__device__ __forceinline__ ushort f2bf(float f){
  uint32_t u = __float_as_uint(f);
  u += 0x7fffu + ((u >> 16) & 1u);
  return (ushort)(u >> 16);
}
__device__ __forceinline__ float bf2f(ushort h){ return __uint_as_float(((uint32_t)h) << 16); }

// ---------------- D2 = data @ W4^T + b4 (once per launch) ----------------
__global__ __launch_bounds__(256) void d2p_kernel(
    const float* __restrict__ data, const float* __restrict__ W4, float* __restrict__ Pd2)
{
  __shared__ float As[16][64];
  __shared__ float Bs[16][64];
  const int tb = blockIdx.x / 7;
  const int ch = blockIdx.x % 7;
  const int kb = ch * 112;
  const int R0 = (tb >> 4) << 6;
  const int C0 = (tb & 15) << 6;
  const int tid = threadIdx.x;
  const int ty = tid >> 4, tx = tid & 15;
  const int mA = tid >> 2, kqA = (tid & 3) << 2;
  float acc[4][4] = {{0.f}};
  for (int kk = 0; kk < 112; kk += 16){
    const float4 a = *(const float4*)&data[(R0+mA)*784 + kb + kk + kqA];
    As[kqA+0][mA]=a.x; As[kqA+1][mA]=a.y; As[kqA+2][mA]=a.z; As[kqA+3][mA]=a.w;
    const float4 b = *(const float4*)&W4[(C0+mA)*784 + kb + kk + kqA];
    Bs[kqA+0][mA]=b.x; Bs[kqA+1][mA]=b.y; Bs[kqA+2][mA]=b.z; Bs[kqA+3][mA]=b.w;
    __syncthreads();
#pragma unroll
    for (int k=0;k<16;k++){
      const float4 av = *(const float4*)&As[k][ty<<2];
      const float4 bv = *(const float4*)&Bs[k][tx<<2];
      acc[0][0]=fmaf(av.x,bv.x,acc[0][0]); acc[0][1]=fmaf(av.x,bv.y,acc[0][1]);
      acc[0][2]=fmaf(av.x,bv.z,acc[0][2]); acc[0][3]=fmaf(av.x,bv.w,acc[0][3]);
      acc[1][0]=fmaf(av.y,bv.x,acc[1][0]); acc[1][1]=fmaf(av.y,bv.y,acc[1][1]);
      acc[1][2]=fmaf(av.y,bv.z,acc[1][2]); acc[1][3]=fmaf(av.y,bv.w,acc[1][3]);
      acc[2][0]=fmaf(av.z,bv.x,acc[2][0]); acc[2][1]=fmaf(av.z,bv.y,acc[2][1]);
      acc[2][2]=fmaf(av.z,bv.z,acc[2][2]); acc[2][3]=fmaf(av.z,bv.w,acc[2][3]);
      acc[3][0]=fmaf(av.w,bv.x,acc[3][0]); acc[3][1]=fmaf(av.w,bv.y,acc[3][1]);
      acc[3][2]=fmaf(av.w,bv.z,acc[3][2]); acc[3][3]=fmaf(av.w,bv.w,acc[3][3]);
    }
    __syncthreads();
  }
  float* P = Pd2 + ch*262144;
#pragma unroll
  for (int i=0;i<4;i++){
    const int r = R0 + (ty<<2) + i;
    float4 o; float* op=(float*)&o;
#pragma unroll
    for (int j=0;j<4;j++) op[j] = acc[i][j];
    *(float4*)&P[r*1024 + C0 + (tx<<2)] = o;
  }
}

__global__ __launch_bounds__(256) void d2r_kernel(
    const float* __restrict__ Pd2, const float* __restrict__ b4, float* __restrict__ D2)
{
  const int e = (blockIdx.x*256 + threadIdx.x) << 2;
  float4 acc = *(const float4*)&Pd2[e];
#pragma unroll
  for (int p = 1; p < 7; ++p){
    const float4 q = *(const float4*)&Pd2[p*262144 + e];
    acc.x += q.x; acc.y += q.y; acc.z += q.z; acc.w += q.w;
  }
  const float4 bb = *(const float4*)&b4[e & 1023];
  acc.x += bb.x; acc.y += bb.y; acc.z += bb.z; acc.w += bb.w;
  *(float4*)&D2[e] = acc;
}

// ---------------- grid barrier ----------------
__device__ __forceinline__ void gbar(unsigned* bar, unsigned target){
  __syncthreads();
  if (threadIdx.x == 0){
    __hip_atomic_fetch_add(bar, 1u, __ATOMIC_RELEASE, __HIP_MEMORY_SCOPE_AGENT);
    unsigned it = 0;
    while (__hip_atomic_load(bar, __ATOMIC_ACQUIRE, __HIP_MEMORY_SCOPE_AGENT) < target){
      __builtin_amdgcn_s_sleep(4);
      if (++it > (1u<<26)) break;
    }
  }
  __syncthreads();
}

// ---------------- persistent kernel ----------------
// 256 blocks x 512 threads (8 waves). Block: unit=bid>>1 (g2, coltile), sub=bid&1 (128 rows).
// Wave w owns rows w*16..w*16+15 x 16 cols; stages its own A rows via global_load_lds
// (double-buffered, XOR-swizzled, vmcnt-counted). B hi/lo resident in LDS.
__global__ __launch_bounds__(512) void persist_kernel(
    const float* __restrict__ data, const float* __restrict__ s0i,
    const float* __restrict__ s1i, const float* __restrict__ s2i,
    const float* __restrict__ W1g, const float* __restrict__ W2,
    const float* __restrict__ W3, const float* __restrict__ b0g,
    const float* __restrict__ b2g, const float* __restrict__ D2,
    float* __restrict__ sp0A, float* __restrict__ sp0B,
    float* __restrict__ sp1A, float* __restrict__ sp1B,
    ushort* __restrict__ sp2A, ushort* __restrict__ sp2B,
    ushort* __restrict__ ahA, ushort* __restrict__ ahB,
    ushort* __restrict__ alA, ushort* __restrict__ alB,
    float* __restrict__ out, unsigned* __restrict__ bar)
{
  extern __shared__ char lds[];
  short* Bh   = (short*)lds;                 // [kg 128][col 16][8] shorts = 32KB
  short* Bl   = (short*)(lds + 32768);       // 32KB
  short* Abuf = (short*)(lds + 65536);       // 64KB: wave w at w*4096 shorts: [arr2][buf2][1024]
  float* Sst  = (float*)(lds + 131072);      // [128][16] = 8KB
  float* AUX  = (float*)(lds + 139264);      // 8KB: g2? D2 slice : sp0 slice [128][10]
  float* MISC = (float*)(lds + 147456);      // 2KB
  uint32_t* K  = (uint32_t*)MISC;            // 6
  float* b0s   = MISC + 8;                   // 10
  float* s0st  = MISC + 18;                  // 10
  float* s0red = MISC + 28;                  // 80
  float* b2s   = MISC + 108;                 // 16
  float* W1epi = MISC + 124;                 // 160

  const int bid = blockIdx.x, tid = threadIdx.x;
  const int unit = bid >> 1, sub = bid & 1;
  const int g2 = unit >> 6, cb = (unit & 63) << 4;
  const int w = tid >> 6, lane = tid & 63, lr = lane & 15, sl = lane >> 4;

  // ======== preamble: fill LDS ========
  { // B slice (16 cols of W2/W3), split hi/lo
    const float* Wsrc = g2 ? W3 : W2;
    const int row = tid >> 5, seg = tid & 31;
    const float* src = &Wsrc[(cb + row)*1024 + seg*32];
#pragma unroll
    for (int g = 0; g < 4; ++g){
      short8 h8, l8;
#pragma unroll
      for (int j = 0; j < 8; ++j){
        const float f = src[g*8 + j];
        const ushort hh = f2bf(f);
        h8[j] = (short)hh;
        l8[j] = (short)f2bf(f - bf2f(hh));
      }
      const int kg = seg*4 + g;
      *(short8*)&Bh[(kg<<7) + (row<<3)] = h8;
      *(short8*)&Bl[(kg<<7) + (row<<3)] = l8;
    }
  }
  for (int i = tid; i < 160; i += 512) W1epi[i] = W1g[(cb + i/10)*10 + (i%10)];
  {
    const float* Ssrc = g2 ? s2i : s1i;
    for (int idx = tid; idx < 2048; idx += 512){
      const int r = idx >> 4, c = idx & 15;
      Sst[idx] = Ssrc[(((sub<<7)+r)<<10) + cb + c];
    }
    if (g2){
      for (int idx = tid; idx < 2048; idx += 512){
        const int r = idx >> 4, c = idx & 15;
        AUX[idx] = D2[(((sub<<7)+r)<<10) + cb + c];
      }
    }
  }
  if (tid < 10){ b0s[tid] = b0g[tid]; s0st[tid] = s0i[bid*10 + tid]; }
  if (tid < 16) b2s[tid] = b2g[cb + tid];
  for (int idx = tid; idx < 784; idx += 512)
    out[526848 + bid*784 + idx] = data[bid*784 + idx];
  if (tid == 0) step_keys(0, K);
  __syncthreads();

  // spikes(0)
  {
    const uint32_t kk0 = g2 ? K[4] : K[2];
    const uint32_t kk1 = g2 ? K[5] : K[3];
    for (int idx = tid; idx < 2048; idx += 512){
      const int r = (sub<<7) + (idx >> 4);
      const int c = cb + (idx & 15);
      const int e = (r << 10) + c;
      const float v = fminf(fmaxf(Sst[idx], 0.f), 1.f);
      uint32_t x0 = 0u, x1 = (uint32_t)e;
      tf2x32(kk0, kk1, x0, x1);
      const bool sp = (u01(x0 ^ x1) < v);
      if (!g2){
        sp1A[e] = sp ? 1.0f : 0.0f;
        const ushort hh = f2bf(v);
        ahA[e] = hh; alA[e] = f2bf(v - bf2f(hh));
      } else {
        sp2A[e] = sp ? (ushort)0x3F80u : (ushort)0u;
      }
    }
    if (tid < 10){
      const float v = fminf(fmaxf(s0st[tid], 0.f), 1.f);
      const int e = bid*10 + tid;
      uint32_t x0 = 0u, x1 = (uint32_t)e;
      tf2x32(K[0], K[1], x0, x1);
      sp0A[e] = (u01(x0 ^ x1) < v) ? 1.0f : 0.0f;
    }
  }
  unsigned phase = 1;
  gbar(bar, 256u*phase); phase++;

  // per-thread GEMM constants
  const int r0g   = (sub << 7) + (w << 4);         // wave's global row base
  const int lrow  = lane >> 3, lseg = lane & 7;    // staging lane mapping
  const int lbase = ((r0g + lrow) << 10) + ((lseg ^ lrow) << 3);  // swizzled global src (elems)
  const int aoff0 = (lr << 6) + ((sl ^ (lr & 7)) << 3);           // swizzled ds_read (elems)
  const int aoff1 = (lr << 6) + (((4 + sl) ^ (lr & 7)) << 3);
  short* AW = Abuf + (w << 12);                    // wave-private A region

#pragma unroll 1
  for (int t = 0; t < 30; ++t){
    const int cur = t & 1;
    const float*  sp0c = cur ? sp0B : sp0A;  float*  sp0n = cur ? sp0A : sp0B;
    const float*  sp1c = cur ? sp1B : sp1A;  float*  sp1n = cur ? sp1A : sp1B;
    const ushort* sp2c = cur ? sp2B : sp2A;  ushort* sp2n = cur ? sp2A : sp2B;
    const ushort* ahc  = cur ? ahB  : ahA;   ushort* ahn  = cur ? ahA  : ahB;
    const ushort* alc  = cur ? alB  : alA;   ushort* aln  = cur ? alA  : alB;

    if (tid == 0) step_keys(t+1, K);
    if (!g2){
      for (int idx = tid; idx < 1280; idx += 512) AUX[idx] = sp0c[sub*1280 + idx];
    }
    __syncthreads();

    // ---- s0 duty: row r = bid ----
    {
      float a0_[10] = {0.f,0.f,0.f,0.f,0.f,0.f,0.f,0.f,0.f,0.f};
      const float* sp1r = sp1c + (bid << 10);
#pragma unroll
      for (int q = 0; q < 2; ++q){
        const int k = (q << 9) + tid;
        const float sv = sp1r[k];
        const float* w1k = &W1g[k*10];
#pragma unroll
        for (int c2 = 0; c2 < 10; ++c2) a0_[c2] = fmaf(sv, w1k[c2], a0_[c2]);
      }
#pragma unroll
      for (int c2 = 0; c2 < 10; ++c2){
        float v = a0_[c2];
        v += __shfl_xor(v, 1);  v += __shfl_xor(v, 2);  v += __shfl_xor(v, 4);
        v += __shfl_xor(v, 8);  v += __shfl_xor(v, 16); v += __shfl_xor(v, 32);
        a0_[c2] = v;
      }
      if (lane == 0){
#pragma unroll
        for (int c2 = 0; c2 < 10; ++c2) s0red[w*10 + c2] = a0_[c2];
      }
      __syncthreads();
      if (tid < 10){
        float sum = 0.f;
#pragma unroll
        for (int ww = 0; ww < 8; ++ww) sum += s0red[ww*10 + tid];
        const float s = s0st[tid];
        float nv = s + DTv*(-s + sum + b0s[tid]);
        nv = fminf(fmaxf(nv, 0.f), 1.f);
        s0st[tid] = nv;
        const int e = bid*10 + tid;
        uint32_t x0 = 0u, x1 = (uint32_t)e;
        tf2x32(K[0], K[1], x0, x1);
        sp0n[e] = (u01(x0 ^ x1) < nv) ? 1.0f : 0.0f;
      }
    }

    // ---- GEMM: wave-private staged A, LDS-resident B ----
    f32x4 acc0 = {0.f,0.f,0.f,0.f}, acc1 = {0.f,0.f,0.f,0.f}, acc2 = {0.f,0.f,0.f,0.f};
    if (!g2){
      const short* A0 = (const short*)sp2c;
      GLOAD16(A0 + lbase,        AW);
      GLOAD16(A0 + lbase + 8192, AW + 512);
#pragma unroll 2
      for (int c = 0; c < 16; ++c){
        const int b = c & 1;
        if (c < 15){
          const int nb = b ^ 1;
          const short* gsrc = A0 + lbase + ((c+1) << 6);
          GLOAD16(gsrc,        AW + (nb<<10));
          GLOAD16(gsrc + 8192, AW + (nb<<10) + 512);
          asm volatile("s_waitcnt vmcnt(2)" ::: "memory");
        } else {
          asm volatile("s_waitcnt vmcnt(0)" ::: "memory");
        }
        __builtin_amdgcn_sched_barrier(0);
#pragma unroll
        for (int ks = 0; ks < 2; ++ks){
          const short8 a8 = *(const short8*)(AW + (b<<10) + (ks ? aoff1 : aoff0));
          const int ib = (((c<<3) + (ks<<2) + sl) << 7) + (lr<<3);
          const short8 bh8 = *(const short8*)(Bh + ib);
          const short8 bl8 = *(const short8*)(Bl + ib);
          acc0 = MFMA16(a8, bh8, acc0);
          acc1 = MFMA16(a8, bl8, acc1);
        }
      }
    } else {
      const short* Ah = (const short*)ahc;
      const short* Al = (const short*)alc;
      GLOAD16(Ah + lbase,        AW);
      GLOAD16(Ah + lbase + 8192, AW + 512);
      GLOAD16(Al + lbase,        AW + 2048);
      GLOAD16(Al + lbase + 8192, AW + 2048 + 512);
#pragma unroll 2
      for (int c = 0; c < 16; ++c){
        const int b = c & 1;
        if (c < 15){
          const int nb = b ^ 1;
          const int go = (c+1) << 6;
          GLOAD16(Ah + lbase + go,        AW + (nb<<10));
          GLOAD16(Ah + lbase + 8192 + go, AW + (nb<<10) + 512);
          GLOAD16(Al + lbase + go,        AW + 2048 + (nb<<10));
          GLOAD16(Al + lbase + 8192 + go, AW + 2048 + (nb<<10) + 512);
          asm volatile("s_waitcnt vmcnt(4)" ::: "memory");
        } else {
          asm volatile("s_waitcnt vmcnt(0)" ::: "memory");
        }
        __builtin_amdgcn_sched_barrier(0);
#pragma unroll
        for (int ks = 0; ks < 2; ++ks){
          const int ao = (b<<10) + (ks ? aoff1 : aoff0);
          const short8 h8 = *(const short8*)(AW + ao);
          const short8 l8 = *(const short8*)(AW + 2048 + ao);
          const int ib = (((c<<3) + (ks<<2) + sl) << 7) + (lr<<3);
          const short8 bh8 = *(const short8*)(Bh + ib);
          const short8 bl8 = *(const short8*)(Bl + ib);
          acc0 = MFMA16(h8, bh8, acc0);
          acc1 = MFMA16(h8, bl8, acc1);
          acc2 = MFMA16(l8, bh8, acc2);
        }
      }
    }

    // ---- epilogue: 4 outputs/lane ----
    {
      const uint32_t kk0 = g2 ? K[4] : K[2];
      const uint32_t kk1 = g2 ? K[5] : K[3];
      const bool emit = (t < 29);
#pragma unroll
      for (int i2 = 0; i2 < 4; ++i2){
        const int rloc = (w<<4) + (sl<<2) + i2;
        float v = acc0[i2] + acc1[i2] + acc2[i2];
        const int e = (((sub<<7) + rloc) << 10) + cb + lr;
        if (!g2){
          float sm = 0.f;
#pragma unroll
          for (int k2 = 0; k2 < 10; ++k2)
            sm = fmaf(AUX[rloc*10 + k2], W1epi[lr*10 + k2], sm);
          v += b2s[lr] + sm;
        } else {
          v += AUX[(rloc<<4) + lr];
        }
        const float s = Sst[(rloc<<4) + lr];
        float nv = s + DTv*(-s + v);
        nv = fminf(fmaxf(nv, 0.f), 1.f);
        Sst[(rloc<<4) + lr] = nv;
        if (emit){
          uint32_t x0 = 0u, x1 = (uint32_t)e;
          tf2x32(kk0, kk1, x0, x1);
          const bool sp = (u01(x0 ^ x1) < nv);
          if (!g2){
            sp1n[e] = sp ? 1.0f : 0.0f;
            const ushort hh = f2bf(nv);
            ahn[e] = hh; aln[e] = f2bf(nv - bf2f(hh));
          } else {
            sp2n[e] = sp ? (ushort)0x3F80u : (ushort)0u;
          }
        }
      }
    }

    if (t < 29){ gbar(bar, 256u*phase); phase++; }
  }

  // ======== final output ========
  __syncthreads();
  for (int idx = tid; idx < 2048; idx += 512){
    const int r = (sub<<7) + (idx >> 4);
    const int c = cb + (idx & 15);
    out[(g2 ? 264704 : 2560) + (r << 10) + c] = Sst[idx];
  }
  if (tid < 10) out[bid*10 + tid] = s0st[tid];
}

// ---------------- host ----------------
extern "C" void kernel_launch(void* const* d_in, const int* in_sizes, int n_in,
                              void* d_out, int out_size, void* d_ws, size_t ws_size,
                              hipStream_t stream)
{
  const float* data = (const float*)d_in[0];
  const float* s0i  = (const float*)d_in[1];
  const float* s1i  = (const float*)d_in[2];
  const float* s2i  = (const float*)d_in[3];
  const float* b0   = (const float*)d_in[5];
  const float* W1   = (const float*)d_in[6];
  const float* W2   = (const float*)d_in[7];
  const float* b2   = (const float*)d_in[8];
  const float* W3   = (const float*)d_in[9];
  const float* W4   = (const float*)d_in[10];
  const float* b4   = (const float*)d_in[11];
  float* out = (float*)d_out;
  float* ws  = (float*)d_ws;

  // ws layout (float offsets), ~13.7 MB
  float* sp0A = ws + 0;         // 2560
  float* sp0B = ws + 2560;      // 2560
  float* sp1A = ws + 5120;      // 262144
  float* sp1B = ws + 267264;    // 262144
  float* D2   = ws + 529408;    // 262144
  float* Pd2  = ws + 791552;    // 1835008
  ushort* sp2A = (ushort*)(ws + 2626560);  // 262144 ushorts each
  ushort* sp2B = (ushort*)(ws + 2757632);
  ushort* ahA  = (ushort*)(ws + 2888704);
  ushort* ahB  = (ushort*)(ws + 3019776);
  ushort* alA  = (ushort*)(ws + 3150848);
  ushort* alB  = (ushort*)(ws + 3281920);
  unsigned* bar = (unsigned*)(ws + 3412992);

  hipMemsetAsync(bar, 0, 64, stream);
  d2p_kernel<<<448,256,0,stream>>>(data, W4, Pd2);
  d2r_kernel<<<256,256,0,stream>>>(Pd2, b4, D2);
  persist_kernel<<<256,512,149504,stream>>>(
      data, s0i, s1i, s2i, W1, W2, W3, b0, b2, D2,
      sp0A, sp0B, sp1A, sp1B, sp2A, sp2B, ahA, ahB, alA, alB,
      out, bar);
}